// Round 1
// baseline (222.133 us; speedup 1.0000x reference)
//
#include <hip/hip_runtime.h>
#include <hip/hip_bf16.h>
#include <stdint.h>

typedef __attribute__((ext_vector_type(8))) __bf16 bf16x8;
typedef __attribute__((ext_vector_type(4))) __bf16 bf16x4;
typedef __attribute__((ext_vector_type(4))) float f32x4;
typedef __attribute__((ext_vector_type(8))) unsigned short u16x8;

#define DEVI __device__ __forceinline__

DEVI void gload16(const void* g, void* l) {
  __builtin_amdgcn_global_load_lds((const __attribute__((address_space(1))) void*)g,
                                   (__attribute__((address_space(3))) void*)l, 16, 0, 0);
}

// ---------------- convert x fp32 -> bf16 ----------------
__global__ __launch_bounds__(256) void cvt_x_k(const float* __restrict__ x,
                                               __bf16* __restrict__ xb, int n4) {
  int i = blockIdx.x * blockDim.x + threadIdx.x;
  int stride = gridDim.x * blockDim.x;
  for (; i < n4; i += stride) {
    float4 v = ((const float4*)x)[i];
    bf16x4 o;
    o[0] = (__bf16)v.x; o[1] = (__bf16)v.y; o[2] = (__bf16)v.z; o[3] = (__bf16)v.w;
    ((bf16x4*)xb)[i] = o;
  }
}

// ---------------- transpose 4 weights fp32 -> bf16, WT[(plane*768+n)*768 + k] = W[k][n]
__global__ __launch_bounds__(256) void wtrans_k(const float* __restrict__ wq,
                                                const float* __restrict__ wk,
                                                const float* __restrict__ wv,
                                                const float* __restrict__ wp,
                                                __bf16* __restrict__ WT) {
  __shared__ float tile[32][33];
  const float* W = (blockIdx.z == 0) ? wq : (blockIdx.z == 1) ? wk : (blockIdx.z == 2) ? wv : wp;
  int n0 = blockIdx.x * 32, k0 = blockIdx.y * 32;
  int tx = threadIdx.x, ty = threadIdx.y;  // 32 x 8
#pragma unroll
  for (int j = 0; j < 4; ++j)
    tile[ty + 8 * j][tx] = W[(size_t)(k0 + ty + 8 * j) * 768 + n0 + tx];
  __syncthreads();
#pragma unroll
  for (int j = 0; j < 4; ++j)
    WT[(size_t)(blockIdx.z * 768 + n0 + ty + 8 * j) * 768 + k0 + tx] =
        (__bf16)tile[tx][ty + 8 * j];
}

// ---------------- GEMM: C[M x N] = A[M x K] * B^T(rows=n)  (bf16 in, fp32 acc)
// EPI=1: fused rotary+rmsnorm epilogue, bf16 out (QKV, ldc=2304)
// EPI=0: plain fp32 out
template <int EPI>
__global__ __launch_bounds__(256) void gemm_k(const __bf16* __restrict__ A,
                                              const __bf16* __restrict__ B,
                                              void* __restrict__ Cout,
                                              const float* __restrict__ cosT,
                                              const float* __restrict__ sinT,
                                              int K, int lda, int ldb, int ldc) {
  __shared__ __align__(16) __bf16 Al[128 * 32];
  __shared__ __align__(16) __bf16 Bl[128 * 32];
  const int tid = threadIdx.x, lane = tid & 63, w = tid >> 6;
  const int wm = w >> 1, wn = w & 1;
  const int m0 = blockIdx.y * 128, n0 = blockIdx.x * 128;
  const int c = lane & 15, g = lane >> 4;
  f32x4 acc[4][4] = {};

  for (int k0 = 0; k0 < K; k0 += 32) {
#pragma unroll
    for (int i = 0; i < 2; ++i) {
      int e = (i * 256 + tid) * 8;  // elem offset in 128x32 tile
      int row = e >> 5, col = e & 31;
      gload16(A + (size_t)(m0 + row) * lda + k0 + col, (char*)Al + 2 * (size_t)e);
      gload16(B + (size_t)(n0 + row) * ldb + k0 + col, (char*)Bl + 2 * (size_t)e);
    }
    __syncthreads();
    bf16x8 af[4], bfr[4];
#pragma unroll
    for (int q = 0; q < 4; ++q)
      af[q] = *(const bf16x8*)&Al[(wm * 64 + q * 16 + c) * 32 + 8 * g];
#pragma unroll
    for (int q = 0; q < 4; ++q)
      bfr[q] = *(const bf16x8*)&Bl[(wn * 64 + q * 16 + c) * 32 + 8 * g];
#pragma unroll
    for (int mf = 0; mf < 4; ++mf)
#pragma unroll
      for (int nf = 0; nf < 4; ++nf)
        acc[mf][nf] = __builtin_amdgcn_mfma_f32_16x16x32_bf16(af[mf], bfr[nf],
                                                              acc[mf][nf], 0, 0, 0);
    __syncthreads();
  }

  if (EPI == 1) {
    __bf16* out = (__bf16*)Cout;
    const int colbase = n0 + wn * 64;       // multiple of 64 (one head-plane)
    const int plane = colbase / 768;        // 0=q,1=k,2=v
#pragma unroll
    for (int mf = 0; mf < 4; ++mf) {
#pragma unroll
      for (int r = 0; r < 4; ++r) {
        int row = m0 + wm * 64 + mf * 16 + 4 * g + r;
        float v0 = acc[mf][0][r], v1 = acc[mf][1][r], v2 = acc[mf][2][r], v3 = acc[mf][3][r];
        float y0, y1, y2, y3;
        if (plane < 2) {
          int t = row & 2047;
          float c0 = cosT[t * 32 + c],      s0 = sinT[t * 32 + c];
          float c1 = cosT[t * 32 + 16 + c], s1 = sinT[t * 32 + 16 + c];
          y0 = v0 * c0 + v2 * s0;
          y2 = v2 * c0 - v0 * s0;
          y1 = v1 * c1 + v3 * s1;
          y3 = v3 * c1 - v1 * s1;
          float ss = y0 * y0 + y1 * y1 + y2 * y2 + y3 * y3;
          ss += __shfl_xor(ss, 1); ss += __shfl_xor(ss, 2);
          ss += __shfl_xor(ss, 4); ss += __shfl_xor(ss, 8);
          float rn = rsqrtf(ss * (1.0f / 64.0f) + 1e-6f);
          y0 *= rn; y1 *= rn; y2 *= rn; y3 *= rn;
        } else {
          y0 = v0; y1 = v1; y2 = v2; y3 = v3;
        }
        size_t base = (size_t)row * ldc + colbase + c;
        out[base +  0] = (__bf16)y0;
        out[base + 16] = (__bf16)y1;
        out[base + 32] = (__bf16)y2;
        out[base + 48] = (__bf16)y3;
      }
    }
  } else {
    float* out = (float*)Cout;
#pragma unroll
    for (int mf = 0; mf < 4; ++mf)
#pragma unroll
      for (int nf = 0; nf < 4; ++nf)
#pragma unroll
        for (int r = 0; r < 4; ++r) {
          int row = m0 + wm * 64 + mf * 16 + 4 * g + r;
          out[(size_t)row * ldc + n0 + wn * 64 + nf * 16 + c] = acc[mf][nf][r];
        }
  }
}

// ---------------- flash attention (no mask), QBLK=64 (4 waves x 16 rows), KVBLK=128
__global__ __launch_bounds__(256) void attn_k(const __bf16* __restrict__ QKV,
                                              __bf16* __restrict__ Yb) {
  constexpr int TT = 2048;
  __shared__ __align__(16) __bf16 Kl[128 * 64];   // swizzled: slot s holds logical slot s^(row&7)
  __shared__ __align__(16) __bf16 Vl[64 * 128];   // transposed [d][key], swizzled bits4-7 ^= d&15
  __shared__ __align__(16) __bf16 Pl[4][16 * 136];
  const int tid = threadIdx.x, lane = tid & 63, w = tid >> 6;
  const int c = lane & 15, g = lane >> 4;
  const int qb = blockIdx.x, bh = blockIdx.y;
  const int b = bh / 12, h = bh % 12;
  const size_t ldq = 2304;
  const __bf16* Qg = QKV + (size_t)(b * TT) * ldq + h * 64;
  const __bf16* Kg = QKV + (size_t)(b * TT) * ldq + 768 + h * 64;
  const __bf16* Vg = QKV + (size_t)(b * TT) * ldq + 1536 + h * 64;

  bf16x8 aq0, aq1;
  {
    int row = qb * 64 + w * 16 + c;
    aq0 = *(const bf16x8*)(Qg + (size_t)row * ldq + 8 * g);
    aq1 = *(const bf16x8*)(Qg + (size_t)row * ldq + 32 + 8 * g);
  }

  f32x4 Yacc[4] = {};
  float m_run[4], l_run[4];
#pragma unroll
  for (int r = 0; r < 4; ++r) { m_run[r] = -__builtin_inff(); l_run[r] = 0.f; }

  for (int kv0 = 0; kv0 < TT; kv0 += 128) {
    // ---- stage K via global_load_lds with pre-swizzled source (linear LDS dest)
#pragma unroll
    for (int p = 0; p < 4; ++p) {
      int cid = p * 256 + tid;
      int row = cid >> 3, s = cid & 7;
      int srccol = 8 * (s ^ (row & 7));
      gload16(Kg + (size_t)(kv0 + row) * ldq + srccol, (char*)Kl + row * 128 + 16 * s);
    }
    // ---- stage V transposed: pair-packed b32 swizzled writes
#pragma unroll
    for (int p = 0; p < 2; ++p) {
      int u = p * 256 + tid;
      int kp = u >> 3, d0 = (u & 7) * 8;
      const __bf16* src0 = Vg + (size_t)(kv0 + 2 * kp) * ldq + d0;
      u16x8 v0 = *(const u16x8*)src0;
      u16x8 v1 = *(const u16x8*)(src0 + ldq);
#pragma unroll
      for (int i = 0; i < 8; ++i) {
        int d = d0 + i;
        int byte = (d * 256 + 4 * kp) ^ ((d & 15) << 4);
        uint32_t pk = (uint32_t)v0[i] | ((uint32_t)v1[i] << 16);
        *(uint32_t*)((char*)Vl + byte) = pk;
      }
    }
    __syncthreads();

    // ---- S = Q K^T  (16 q-rows x 128 keys per wave)
    f32x4 Sf[8];
    const f32x4 zero = {0.f, 0.f, 0.f, 0.f};
#pragma unroll
    for (int j = 0; j < 8; ++j) {
      int row = j * 16 + c;
      int sw = row & 7;
      bf16x8 bk0 = *(const bf16x8*)((char*)Kl + row * 128 + 16 * (g ^ sw));
      bf16x8 bk1 = *(const bf16x8*)((char*)Kl + row * 128 + 16 * ((g + 4) ^ sw));
      Sf[j] = __builtin_amdgcn_mfma_f32_16x16x32_bf16(aq0, bk0, zero, 0, 0, 0);
      Sf[j] = __builtin_amdgcn_mfma_f32_16x16x32_bf16(aq1, bk1, Sf[j], 0, 0, 0);
    }

    // ---- online softmax (scale 1/8), P -> Pl (bf16)
#pragma unroll
    for (int r = 0; r < 4; ++r) {
      float mx = Sf[0][r];
#pragma unroll
      for (int j = 1; j < 8; ++j) mx = fmaxf(mx, Sf[j][r]);
      mx = fmaxf(mx, __shfl_xor(mx, 1));
      mx = fmaxf(mx, __shfl_xor(mx, 2));
      mx = fmaxf(mx, __shfl_xor(mx, 4));
      mx = fmaxf(mx, __shfl_xor(mx, 8));
      mx *= 0.125f;
      float mnew = fmaxf(m_run[r], mx);
      float corr = __expf(m_run[r] - mnew);
      float rs = 0.f;
#pragma unroll
      for (int j = 0; j < 8; ++j) {
        float p = __expf(Sf[j][r] * 0.125f - mnew);
        rs += p;
        Pl[w][(4 * g + r) * 136 + j * 16 + c] = (__bf16)p;
      }
      rs += __shfl_xor(rs, 1); rs += __shfl_xor(rs, 2);
      rs += __shfl_xor(rs, 4); rs += __shfl_xor(rs, 8);
      l_run[r] = l_run[r] * corr + rs;
      m_run[r] = mnew;
#pragma unroll
      for (int dn = 0; dn < 4; ++dn) Yacc[dn][r] *= corr;
    }
    __syncthreads();

    // ---- Y += P V
#pragma unroll
    for (int kk = 0; kk < 4; ++kk) {
      bf16x8 ap = *(const bf16x8*)&Pl[w][c * 136 + kk * 32 + 8 * g];
#pragma unroll
      for (int dn = 0; dn < 4; ++dn) {
        int d = dn * 16 + c;
        int byte = (d * 256 + kk * 64 + 16 * g) ^ ((d & 15) << 4);
        bf16x8 bv = *(const bf16x8*)((char*)Vl + byte);
        Yacc[dn] = __builtin_amdgcn_mfma_f32_16x16x32_bf16(ap, bv, Yacc[dn], 0, 0, 0);
      }
    }
    __syncthreads();
  }

  // ---- epilogue: divide by l, write bf16
#pragma unroll
  for (int dn = 0; dn < 4; ++dn)
#pragma unroll
    for (int r = 0; r < 4; ++r) {
      float y = Yacc[dn][r] / l_run[r];
      int row = qb * 64 + w * 16 + 4 * g + r;
      Yb[(size_t)(b * TT + row) * 768 + h * 64 + dn * 16 + c] = (__bf16)y;
    }
}

extern "C" void kernel_launch(void* const* d_in, const int* in_sizes, int n_in,
                              void* d_out, int out_size, void* d_ws, size_t ws_size,
                              hipStream_t stream) {
  const float* x = (const float*)d_in[0];
  const float* cosT = (const float*)d_in[1];
  const float* sinT = (const float*)d_in[2];
  const float* wq = (const float*)d_in[3];
  const float* wk = (const float*)d_in[4];
  const float* wv = (const float*)d_in[5];
  const float* wp = (const float*)d_in[6];

  char* ws = (char*)d_ws;
  __bf16* xb   = (__bf16*)(ws);                 //  6,291,456 B  (4096x768 bf16)
  __bf16* WT   = (__bf16*)(ws + 6291456);       //  4,718,592 B  (3072x768 bf16)
  __bf16* QKVb = (__bf16*)(ws + 11010048);      // 18,874,368 B  (4096x2304 bf16)
  __bf16* Yb   = (__bf16*)(ws + 29884416);      //  6,291,456 B  (4096x768 bf16)

  cvt_x_k<<<2048, 256, 0, stream>>>(x, xb, (4096 * 768) / 4);
  wtrans_k<<<dim3(24, 24, 4), dim3(32, 8), 0, stream>>>(wq, wk, wv, wp, WT);
  // fused QKV gemm: M=4096, N=2304, K=768
  gemm_k<1><<<dim3(18, 32), 256, 0, stream>>>(xb, WT, (void*)QKVb, cosT, sinT,
                                              768, 768, 768, 2304);
  attn_k<<<dim3(32, 24), 256, 0, stream>>>(QKVb, Yb);
  // proj gemm: M=4096, N=768, K=768
  gemm_k<0><<<dim3(6, 32), 256, 0, stream>>>(Yb, WT + (size_t)2304 * 768, d_out,
                                             nullptr, nullptr, 768, 768, 768, 768);
}

// Round 2
// 202.461 us; speedup vs baseline: 1.0972x; 1.0972x over previous
//
#include <hip/hip_runtime.h>
#include <hip/hip_bf16.h>
#include <stdint.h>

typedef __attribute__((ext_vector_type(8))) __bf16 bf16x8;
typedef __attribute__((ext_vector_type(4))) __bf16 bf16x4;
typedef __attribute__((ext_vector_type(2))) __bf16 bf16x2;
typedef __attribute__((ext_vector_type(4))) float f32x4;
typedef __attribute__((ext_vector_type(16))) float f32x16;
typedef __attribute__((ext_vector_type(8))) unsigned short u16x8;
typedef __attribute__((ext_vector_type(4))) unsigned int u32x4;

#define DEVI __device__ __forceinline__

DEVI void gload16(const void* g, void* l) {
  __builtin_amdgcn_global_load_lds((const __attribute__((address_space(1))) void*)g,
                                   (__attribute__((address_space(3))) void*)l, 16, 0, 0);
}

DEVI uint32_t pack2(float a, float b) {
  bf16x2 t;
  t[0] = (__bf16)a;
  t[1] = (__bf16)b;
  return __builtin_bit_cast(uint32_t, t);
}

// ---------------- convert x fp32 -> bf16 ----------------
__global__ __launch_bounds__(256) void cvt_x_k(const float* __restrict__ x,
                                               __bf16* __restrict__ xb, int n4) {
  int i = blockIdx.x * blockDim.x + threadIdx.x;
  int stride = gridDim.x * blockDim.x;
  for (; i < n4; i += stride) {
    float4 v = ((const float4*)x)[i];
    bf16x4 o;
    o[0] = (__bf16)v.x; o[1] = (__bf16)v.y; o[2] = (__bf16)v.z; o[3] = (__bf16)v.w;
    ((bf16x4*)xb)[i] = o;
  }
}

// ---------------- transpose 4 weights fp32 -> bf16, WT[(plane*768+n)*768 + k] = W[k][n]
__global__ __launch_bounds__(256) void wtrans_k(const float* __restrict__ wq,
                                                const float* __restrict__ wk,
                                                const float* __restrict__ wv,
                                                const float* __restrict__ wp,
                                                __bf16* __restrict__ WT) {
  __shared__ float tile[32][33];
  const float* W = (blockIdx.z == 0) ? wq : (blockIdx.z == 1) ? wk : (blockIdx.z == 2) ? wv : wp;
  int n0 = blockIdx.x * 32, k0 = blockIdx.y * 32;
  int tx = threadIdx.x, ty = threadIdx.y;  // 32 x 8
#pragma unroll
  for (int j = 0; j < 4; ++j)
    tile[ty + 8 * j][tx] = W[(size_t)(k0 + ty + 8 * j) * 768 + n0 + tx];
  __syncthreads();
#pragma unroll
  for (int j = 0; j < 4; ++j)
    WT[(size_t)(blockIdx.z * 768 + n0 + ty + 8 * j) * 768 + k0 + tx] =
        (__bf16)tile[tx][ty + 8 * j];
}

// ---------------- GEMM: C[M x N] = A[M x K] * B^T(rows=n)  (bf16 in, fp32 acc)
// EPI=1: fused rotary+rmsnorm epilogue, bf16 out (QKV, ldc=2304); BN=128 only
// EPI=0: plain fp32 out
template <int EPI, int BN>
__global__ __launch_bounds__(256) void gemm_k(const __bf16* __restrict__ A,
                                              const __bf16* __restrict__ B,
                                              void* __restrict__ Cout,
                                              const float* __restrict__ cosT,
                                              const float* __restrict__ sinT,
                                              int K, int lda, int ldb, int ldc) {
  constexpr int NF = BN / 32;  // n-frags per wave
  __shared__ __align__(16) __bf16 Al[128 * 32];
  __shared__ __align__(16) __bf16 Bl[BN * 32];
  const int tid = threadIdx.x, lane = tid & 63, w = tid >> 6;
  const int wm = w >> 1, wn = w & 1;
  const int m0 = blockIdx.y * 128, n0 = blockIdx.x * BN;
  const int c = lane & 15, g = lane >> 4;
  f32x4 acc[4][NF] = {};

  for (int k0 = 0; k0 < K; k0 += 32) {
#pragma unroll
    for (int i = 0; i < 2; ++i) {
      int e = (i * 256 + tid) * 8;  // elem offset in 128x32 tile
      int row = e >> 5, col = e & 31;
      gload16(A + (size_t)(m0 + row) * lda + k0 + col, (char*)Al + 2 * (size_t)e);
    }
#pragma unroll
    for (int i = 0; i < BN / 64; ++i) {
      int e = (i * 256 + tid) * 8;
      int row = e >> 5, col = e & 31;
      gload16(B + (size_t)(n0 + row) * ldb + k0 + col, (char*)Bl + 2 * (size_t)e);
    }
    __syncthreads();
    bf16x8 af[4], bfr[NF];
#pragma unroll
    for (int q = 0; q < 4; ++q)
      af[q] = *(const bf16x8*)&Al[(wm * 64 + q * 16 + c) * 32 + 8 * g];
#pragma unroll
    for (int q = 0; q < NF; ++q)
      bfr[q] = *(const bf16x8*)&Bl[(wn * (BN / 2) + q * 16 + c) * 32 + 8 * g];
#pragma unroll
    for (int mf = 0; mf < 4; ++mf)
#pragma unroll
      for (int nf = 0; nf < NF; ++nf)
        acc[mf][nf] = __builtin_amdgcn_mfma_f32_16x16x32_bf16(af[mf], bfr[nf],
                                                              acc[mf][nf], 0, 0, 0);
    __syncthreads();
  }

  if (EPI == 1) {
    __bf16* out = (__bf16*)Cout;
    const int colbase = n0 + wn * 64;       // multiple of 64 (one head-plane)
    const int plane = colbase / 768;        // 0=q,1=k,2=v
#pragma unroll
    for (int mf = 0; mf < 4; ++mf) {
#pragma unroll
      for (int r = 0; r < 4; ++r) {
        int row = m0 + wm * 64 + mf * 16 + 4 * g + r;
        float v0 = acc[mf][0][r], v1 = acc[mf][1][r], v2 = acc[mf][2][r], v3 = acc[mf][3][r];
        float y0, y1, y2, y3;
        if (plane < 2) {
          int t = row & 2047;
          float c0 = cosT[t * 32 + c],      s0 = sinT[t * 32 + c];
          float c1 = cosT[t * 32 + 16 + c], s1 = sinT[t * 32 + 16 + c];
          y0 = v0 * c0 + v2 * s0;
          y2 = v2 * c0 - v0 * s0;
          y1 = v1 * c1 + v3 * s1;
          y3 = v3 * c1 - v1 * s1;
          float ss = y0 * y0 + y1 * y1 + y2 * y2 + y3 * y3;
          ss += __shfl_xor(ss, 1); ss += __shfl_xor(ss, 2);
          ss += __shfl_xor(ss, 4); ss += __shfl_xor(ss, 8);
          float rn = rsqrtf(ss * (1.0f / 64.0f) + 1e-6f);
          y0 *= rn; y1 *= rn; y2 *= rn; y3 *= rn;
        } else {
          y0 = v0; y1 = v1; y2 = v2; y3 = v3;
        }
        size_t base = (size_t)row * ldc + colbase + c;
        out[base +  0] = (__bf16)y0;
        out[base + 16] = (__bf16)y1;
        out[base + 32] = (__bf16)y2;
        out[base + 48] = (__bf16)y3;
      }
    }
  } else {
    float* out = (float*)Cout;
#pragma unroll
    for (int mf = 0; mf < 4; ++mf)
#pragma unroll
      for (int nf = 0; nf < NF; ++nf)
#pragma unroll
        for (int r = 0; r < 4; ++r) {
          int row = m0 + wm * 64 + mf * 16 + 4 * g + r;
          out[(size_t)row * ldc + n0 + wn * (BN / 2) + nf * 16 + c] = acc[mf][nf][r];
        }
  }
}

// ---------------- flash attention (no mask), swapped-operand 32x32 structure
// 4 waves x 32 q-rows = QBLK 128; KVBLK=128; S^T and Y^T both have q = lane&31.
__global__ __launch_bounds__(256, 2) void attn_k(const __bf16* __restrict__ QKV,
                                                 __bf16* __restrict__ Yb) {
  constexpr int TT = 2048;
  __shared__ __align__(16) char smem[32768];
  __bf16* Kl = (__bf16*)smem;  // [128 keys][64 d], 16B chunks swizzled: slot s holds chunk s^(row&7)
  // Vl at smem+16384: transposed [64 d][128 keys], byte = (d*256 + key*2) ^ ((d&15)<<4)
  const int tid = threadIdx.x, lane = tid & 63, w = tid >> 6;
  const int q5 = lane & 31, h = lane >> 5;
  const int qb = blockIdx.x, bh = blockIdx.y;
  const int b = bh / 12, hd = bh % 12;
  const size_t ldq = 2304;
  const __bf16* Qg = QKV + (size_t)(b * TT) * ldq + hd * 64;
  const __bf16* Kg = QKV + (size_t)(b * TT) * ldq + 768 + hd * 64;
  const __bf16* Vg = QKV + (size_t)(b * TT) * ldq + 1536 + hd * 64;

  // Q fragment (B-operand): lane holds Q[q0+q5][16t + 8h .. +7]
  const int qrow = qb * 128 + w * 32 + q5;
  bf16x8 aq[4];
#pragma unroll
  for (int t = 0; t < 4; ++t)
    aq[t] = *(const bf16x8*)(Qg + (size_t)qrow * ldq + t * 16 + 8 * h);

  f32x16 Yacc[2] = {};  // Y^T[d][q=q5], d = (r&3)+8*(r>>2)+4h+32*dh
  float m_run = -__builtin_inff(), l_run = 0.f;

  for (int kv0 = 0; kv0 < TT; kv0 += 128) {
    // ---- stage K via global_load_lds, pre-swizzled source, linear LDS dest
#pragma unroll
    for (int p = 0; p < 4; ++p) {
      int cid = p * 256 + tid;
      int row = cid >> 3, s = cid & 7;
      int srccol = 8 * (s ^ (row & 7));
      gload16(Kg + (size_t)(kv0 + row) * ldq + srccol, (char*)Kl + row * 128 + 16 * s);
    }
    // ---- stage V transposed: pair-packed b32 swizzled writes
#pragma unroll
    for (int p = 0; p < 2; ++p) {
      int u = p * 256 + tid;
      int kp = u >> 3, d0 = (u & 7) * 8;
      const __bf16* src0 = Vg + (size_t)(kv0 + 2 * kp) * ldq + d0;
      u16x8 v0 = *(const u16x8*)src0;
      u16x8 v1 = *(const u16x8*)(src0 + ldq);
#pragma unroll
      for (int i = 0; i < 8; ++i) {
        int d = d0 + i;
        int byte = (d * 256 + 4 * kp) ^ ((d & 15) << 4);
        uint32_t pk = (uint32_t)v0[i] | ((uint32_t)v1[i] << 16);
        *(uint32_t*)(smem + 16384 + byte) = pk;
      }
    }
    __syncthreads();

    // ---- S^T = mfma(A=K, B=Q): lane owns q=q5; 64 scores per lane (keys j*32 + pat + 4h)
    float p_[64];
#pragma unroll
    for (int j = 0; j < 4; ++j) {
      f32x16 S = {};
#pragma unroll
      for (int t = 0; t < 4; ++t) {
        int row = j * 32 + q5;
        int chunk = (2 * t + h) ^ (q5 & 7);
        bf16x8 kf = *(const bf16x8*)((char*)Kl + row * 128 + 16 * chunk);
        S = __builtin_amdgcn_mfma_f32_32x32x16_bf16(kf, aq[t], S, 0, 0, 0);
      }
#pragma unroll
      for (int r = 0; r < 16; ++r) p_[j * 16 + r] = S[r];
    }

    // ---- in-register online softmax (scale 1/8); per-lane scalar m/l
    float mx = p_[0];
#pragma unroll
    for (int i = 1; i < 64; ++i) mx = fmaxf(mx, p_[i]);
    mx = fmaxf(mx, __shfl_xor(mx, 32));
    float mnew = fmaxf(m_run, mx * 0.125f);
    float corr = __expf(m_run - mnew);
    float rs = 0.f;
#pragma unroll
    for (int i = 0; i < 64; ++i) {
      float p = __expf(fmaf(p_[i], 0.125f, -mnew));
      p_[i] = p;
      rs += p;
    }
    rs += __shfl_xor(rs, 32);
    l_run = l_run * corr + rs;
    m_run = mnew;
#pragma unroll
    for (int dh = 0; dh < 2; ++dh)
#pragma unroll
      for (int r = 0; r < 16; ++r) Yacc[dh][r] *= corr;

    // ---- Y^T += mfma(A=V^T, B=P^T) per 16-key sub-tile
#pragma unroll
    for (int j = 0; j < 4; ++j) {
#pragma unroll
      for (int s = 0; s < 2; ++s) {
        const float* ps = p_ + j * 16 + s * 8;
        uint32_t pk01 = pack2(ps[0], ps[1]);
        uint32_t pk23 = pack2(ps[2], ps[3]);
        uint32_t pk45 = pack2(ps[4], ps[5]);
        uint32_t pk67 = pack2(ps[6], ps[7]);
        uint32_t s01 = (uint32_t)__shfl_xor((int)pk01, 32);
        uint32_t s23 = (uint32_t)__shfl_xor((int)pk23, 32);
        uint32_t s45 = (uint32_t)__shfl_xor((int)pk45, 32);
        uint32_t s67 = (uint32_t)__shfl_xor((int)pk67, 32);
        u32x4 pw;
        pw[0] = h ? s45 : pk01;
        pw[1] = h ? s67 : pk23;
        pw[2] = h ? pk45 : s01;
        pw[3] = h ? pk67 : s23;
        bf16x8 pfrag = __builtin_bit_cast(bf16x8, pw);
        int keyb = j * 64 + s * 32 + 16 * h;  // (32j+16s+8h) keys * 2B
#pragma unroll
        for (int dh = 0; dh < 2; ++dh) {
          int d = dh * 32 + q5;
          int byte = (d * 256 + keyb) ^ ((d & 15) << 4);
          bf16x8 vf = *(const bf16x8*)(smem + 16384 + byte);
          Yacc[dh] = __builtin_amdgcn_mfma_f32_32x32x16_bf16(vf, pfrag, Yacc[dh], 0, 0, 0);
        }
      }
    }
    __syncthreads();
  }

  // ---- epilogue: scale by 1/l, transpose via LDS (reuse smem), coalesced stores
  float rl = __builtin_amdgcn_rcpf(l_run);
  char* yb = smem + w * (32 * 144);  // per-wave [32 q][72 bf16] region (144B rows)
#pragma unroll
  for (int dh = 0; dh < 2; ++dh)
#pragma unroll
    for (int a = 0; a < 4; ++a) {
      bf16x4 pkv;
#pragma unroll
      for (int i = 0; i < 4; ++i) pkv[i] = (__bf16)(Yacc[dh][a * 4 + i] * rl);
      int d0 = a * 8 + 4 * h + 32 * dh;
      *(bf16x4*)(yb + q5 * 144 + d0 * 2) = pkv;
    }
  __bf16* Yrow = Yb + (size_t)(b * TT + qb * 128 + w * 32) * 768 + hd * 64;
#pragma unroll
  for (int k = 0; k < 4; ++k) {
    int chunk = k * 64 + lane;
    int qr = chunk >> 3, sr = chunk & 7;
    bf16x8 vv = *(const bf16x8*)(yb + qr * 144 + sr * 16);
    *(bf16x8*)(Yrow + (size_t)qr * 768 + sr * 8) = vv;
  }
}

extern "C" void kernel_launch(void* const* d_in, const int* in_sizes, int n_in,
                              void* d_out, int out_size, void* d_ws, size_t ws_size,
                              hipStream_t stream) {
  const float* x = (const float*)d_in[0];
  const float* cosT = (const float*)d_in[1];
  const float* sinT = (const float*)d_in[2];
  const float* wq = (const float*)d_in[3];
  const float* wk = (const float*)d_in[4];
  const float* wv = (const float*)d_in[5];
  const float* wp = (const float*)d_in[6];

  char* ws = (char*)d_ws;
  __bf16* xb   = (__bf16*)(ws);                 //  6,291,456 B  (4096x768 bf16)
  __bf16* WT   = (__bf16*)(ws + 6291456);       //  4,718,592 B  (3072x768 bf16)
  __bf16* QKVb = (__bf16*)(ws + 11010048);      // 18,874,368 B  (4096x2304 bf16)
  __bf16* Yb   = (__bf16*)(ws + 29884416);      //  6,291,456 B  (4096x768 bf16)

  cvt_x_k<<<2048, 256, 0, stream>>>(x, xb, (4096 * 768) / 4);
  wtrans_k<<<dim3(24, 24, 4), dim3(32, 8), 0, stream>>>(wq, wk, wv, wp, WT);
  // fused QKV gemm: M=4096, N=2304, K=768
  gemm_k<1, 128><<<dim3(18, 32), 256, 0, stream>>>(xb, WT, (void*)QKVb, cosT, sinT,
                                                   768, 768, 768, 2304);
  attn_k<<<dim3(16, 24), 256, 0, stream>>>(QKVb, Yb);
  // proj gemm: M=4096, N=768, K=768, 128x64 tiles -> 384 blocks
  gemm_k<0, 64><<<dim3(12, 32), 256, 0, stream>>>(Yb, WT + (size_t)2304 * 768, d_out,
                                                  nullptr, nullptr, 768, 768, 768, 768);
}

// Round 3
// 181.647 us; speedup vs baseline: 1.2229x; 1.1146x over previous
//
#include <hip/hip_runtime.h>
#include <hip/hip_bf16.h>
#include <stdint.h>

typedef __attribute__((ext_vector_type(8))) __bf16 bf16x8;
typedef __attribute__((ext_vector_type(4))) __bf16 bf16x4;
typedef __attribute__((ext_vector_type(2))) __bf16 bf16x2;
typedef __attribute__((ext_vector_type(4))) float f32x4;
typedef __attribute__((ext_vector_type(16))) float f32x16;
typedef __attribute__((ext_vector_type(8))) unsigned short u16x8;
typedef __attribute__((ext_vector_type(4))) unsigned int u32x4;

#define DEVI __device__ __forceinline__

DEVI void gload16(const void* g, void* l) {
  __builtin_amdgcn_global_load_lds((const __attribute__((address_space(1))) void*)g,
                                   (__attribute__((address_space(3))) void*)l, 16, 0, 0);
}

DEVI uint32_t pack2(float a, float b) {
  bf16x2 t;
  t[0] = (__bf16)a;
  t[1] = (__bf16)b;
  return __builtin_bit_cast(uint32_t, t);
}

// V swizzle: spreads banks for BOTH key-major writes (d varies in bits 3-5 across
// a kp-group) and d-major reads (d varies in bits 0-4 across lanes).
DEVI int vswz(int d) { return ((d ^ (d >> 3)) & 15) << 4; }

// ---------------- convert x fp32 -> bf16 ----------------
__global__ __launch_bounds__(256) void cvt_x_k(const float* __restrict__ x,
                                               __bf16* __restrict__ xb, int n4) {
  int i = blockIdx.x * blockDim.x + threadIdx.x;
  int stride = gridDim.x * blockDim.x;
  for (; i < n4; i += stride) {
    float4 v = ((const float4*)x)[i];
    bf16x4 o;
    o[0] = (__bf16)v.x; o[1] = (__bf16)v.y; o[2] = (__bf16)v.z; o[3] = (__bf16)v.w;
    ((bf16x4*)xb)[i] = o;
  }
}

// ---------------- transpose 4 weights fp32 -> bf16, WT[(plane*768+n)*768 + k] = W[k][n]
__global__ __launch_bounds__(256) void wtrans_k(const float* __restrict__ wq,
                                                const float* __restrict__ wk,
                                                const float* __restrict__ wv,
                                                const float* __restrict__ wp,
                                                __bf16* __restrict__ WT) {
  __shared__ float tile[32][33];
  const float* W = (blockIdx.z == 0) ? wq : (blockIdx.z == 1) ? wk : (blockIdx.z == 2) ? wv : wp;
  int n0 = blockIdx.x * 32, k0 = blockIdx.y * 32;
  int tx = threadIdx.x, ty = threadIdx.y;  // 32 x 8
#pragma unroll
  for (int j = 0; j < 4; ++j)
    tile[ty + 8 * j][tx] = W[(size_t)(k0 + ty + 8 * j) * 768 + n0 + tx];
  __syncthreads();
#pragma unroll
  for (int j = 0; j < 4; ++j)
    WT[(size_t)(blockIdx.z * 768 + n0 + ty + 8 * j) * 768 + k0 + tx] =
        (__bf16)tile[tx][ty + 8 * j];
}

// ---------------- GEMM: C[M x N] = A[M x K] * B^T(rows=n)  (bf16 in, fp32 acc)
// 2-phase software pipeline: double-buffered LDS, prefetch issued before compute,
// one barrier per K-step (T3-minimum recipe).
// EPI=1: fused rotary+rmsnorm epilogue, bf16 out (QKV, ldc=2304); BN=128 only
// EPI=0: plain fp32 out
template <int EPI, int BN>
__global__ __launch_bounds__(256) void gemm_k(const __bf16* __restrict__ A,
                                              const __bf16* __restrict__ B,
                                              void* __restrict__ Cout,
                                              const float* __restrict__ cosT,
                                              const float* __restrict__ sinT,
                                              int K, int lda, int ldb, int ldc) {
  constexpr int NF = BN / 32;  // n-frags per wave
  __shared__ __align__(16) __bf16 Al[2][128 * 32];
  __shared__ __align__(16) __bf16 Bl[2][BN * 32];
  const int tid = threadIdx.x, lane = tid & 63, w = tid >> 6;
  const int wm = w >> 1, wn = w & 1;
  const int m0 = blockIdx.y * 128, n0 = blockIdx.x * BN;
  const int c = lane & 15, g = lane >> 4;
  f32x4 acc[4][NF] = {};

  auto stage = [&](int k0, int buf) {
#pragma unroll
    for (int i = 0; i < 2; ++i) {
      int e = (i * 256 + tid) * 8;  // elem offset in 128x32 tile
      int row = e >> 5, col = e & 31;
      gload16(A + (size_t)(m0 + row) * lda + k0 + col, (char*)&Al[buf][0] + 2 * (size_t)e);
    }
#pragma unroll
    for (int i = 0; i < BN / 64; ++i) {
      int e = (i * 256 + tid) * 8;
      int row = e >> 5, col = e & 31;
      gload16(B + (size_t)(n0 + row) * ldb + k0 + col, (char*)&Bl[buf][0] + 2 * (size_t)e);
    }
  };

  stage(0, 0);
  __syncthreads();
  const int NIT = K / 32;
  for (int t = 0; t < NIT; ++t) {
    const int cur = t & 1;
    if (t + 1 < NIT) stage((t + 1) * 32, cur ^ 1);
    bf16x8 af[4], bfr[NF];
#pragma unroll
    for (int q = 0; q < 4; ++q)
      af[q] = *(const bf16x8*)&Al[cur][(wm * 64 + q * 16 + c) * 32 + 8 * g];
#pragma unroll
    for (int q = 0; q < NF; ++q)
      bfr[q] = *(const bf16x8*)&Bl[cur][(wn * (BN / 2) + q * 16 + c) * 32 + 8 * g];
#pragma unroll
    for (int mf = 0; mf < 4; ++mf)
#pragma unroll
      for (int nf = 0; nf < NF; ++nf)
        acc[mf][nf] = __builtin_amdgcn_mfma_f32_16x16x32_bf16(af[mf], bfr[nf],
                                                              acc[mf][nf], 0, 0, 0);
    __syncthreads();
  }

  if (EPI == 1) {
    __bf16* out = (__bf16*)Cout;
    const int colbase = n0 + wn * 64;       // multiple of 64 (one head-plane)
    const int plane = colbase / 768;        // 0=q,1=k,2=v
#pragma unroll
    for (int mf = 0; mf < 4; ++mf) {
#pragma unroll
      for (int r = 0; r < 4; ++r) {
        int row = m0 + wm * 64 + mf * 16 + 4 * g + r;
        float v0 = acc[mf][0][r], v1 = acc[mf][1][r], v2 = acc[mf][2][r], v3 = acc[mf][3][r];
        float y0, y1, y2, y3;
        if (plane < 2) {
          int t = row & 2047;
          float c0 = cosT[t * 32 + c],      s0 = sinT[t * 32 + c];
          float c1 = cosT[t * 32 + 16 + c], s1 = sinT[t * 32 + 16 + c];
          y0 = v0 * c0 + v2 * s0;
          y2 = v2 * c0 - v0 * s0;
          y1 = v1 * c1 + v3 * s1;
          y3 = v3 * c1 - v1 * s1;
          float ss = y0 * y0 + y1 * y1 + y2 * y2 + y3 * y3;
          ss += __shfl_xor(ss, 1); ss += __shfl_xor(ss, 2);
          ss += __shfl_xor(ss, 4); ss += __shfl_xor(ss, 8);
          float rn = rsqrtf(ss * (1.0f / 64.0f) + 1e-6f);
          y0 *= rn; y1 *= rn; y2 *= rn; y3 *= rn;
        } else {
          y0 = v0; y1 = v1; y2 = v2; y3 = v3;
        }
        size_t base = (size_t)row * ldc + colbase + c;
        out[base +  0] = (__bf16)y0;
        out[base + 16] = (__bf16)y1;
        out[base + 32] = (__bf16)y2;
        out[base + 48] = (__bf16)y3;
      }
    }
  } else {
    float* out = (float*)Cout;
#pragma unroll
    for (int mf = 0; mf < 4; ++mf)
#pragma unroll
      for (int nf = 0; nf < NF; ++nf)
#pragma unroll
        for (int r = 0; r < 4; ++r) {
          int row = m0 + wm * 64 + mf * 16 + 4 * g + r;
          out[(size_t)row * ldc + n0 + wn * (BN / 2) + nf * 16 + c] = acc[mf][nf][r];
        }
  }
}

// ---------------- flash attention (no mask), swapped-operand 32x32 structure
// 4 waves x 32 q-rows = QBLK 128; KVBLK=128; S^T and Y^T both have q = lane&31.
// Double-buffered K/V with prefetch-before-compute, one barrier per KV tile.
__global__ __launch_bounds__(256, 2) void attn_k(const __bf16* __restrict__ QKV,
                                                 __bf16* __restrict__ Yb) {
  constexpr int TT = 2048;
  constexpr int NT = TT / 128;
  __shared__ __align__(16) char smem[65536];
  // Kbuf[b] = smem + b*16384: [128 keys][128B], 16B chunk s holds logical chunk s^(row&7)
  // Vbuf[b] = smem + 32768 + b*16384: [64 d][256B keys], byte = (d*256 + key*2) ^ vswz(d)
  const int tid = threadIdx.x, lane = tid & 63, w = tid >> 6;
  const int q5 = lane & 31, h = lane >> 5;
  const int qb = blockIdx.x, bh = blockIdx.y;
  const int b = bh / 12, hd = bh % 12;
  const size_t ldq = 2304;
  const __bf16* Qg = QKV + (size_t)(b * TT) * ldq + hd * 64;
  const __bf16* Kg = QKV + (size_t)(b * TT) * ldq + 768 + hd * 64;
  const __bf16* Vg = QKV + (size_t)(b * TT) * ldq + 1536 + hd * 64;

  // Q fragment (B-operand): lane holds Q[qrow][16t + 8h .. +7]
  const int qrow = qb * 128 + w * 32 + q5;
  bf16x8 aq[4];
#pragma unroll
  for (int t = 0; t < 4; ++t)
    aq[t] = *(const bf16x8*)(Qg + (size_t)qrow * ldq + t * 16 + 8 * h);

  u16x8 vr[4];
  auto stageK = [&](int kv0, int buf) {
#pragma unroll
    for (int p = 0; p < 4; ++p) {
      int cid = p * 256 + tid;
      int row = cid >> 3, s = cid & 7;
      int srccol = 8 * (s ^ (row & 7));
      gload16(Kg + (size_t)(kv0 + row) * ldq + srccol,
              smem + buf * 16384 + row * 128 + 16 * s);
    }
  };
  auto loadV = [&](int kv0) {
#pragma unroll
    for (int p = 0; p < 2; ++p) {
      int u = p * 256 + tid;
      int kp = u >> 3, d0 = (u & 7) * 8;
      const __bf16* src0 = Vg + (size_t)(kv0 + 2 * kp) * ldq + d0;
      vr[2 * p] = *(const u16x8*)src0;
      vr[2 * p + 1] = *(const u16x8*)(src0 + ldq);
    }
  };
  auto writeV = [&](int buf) {
    char* vb = smem + 32768 + buf * 16384;
#pragma unroll
    for (int p = 0; p < 2; ++p) {
      int u = p * 256 + tid;
      int kp = u >> 3, d0 = (u & 7) * 8;
#pragma unroll
      for (int i = 0; i < 8; ++i) {
        int d = d0 + i;
        int byte = (d * 256 + 4 * kp) ^ vswz(d);
        uint32_t pk = (uint32_t)vr[2 * p][i] | ((uint32_t)vr[2 * p + 1][i] << 16);
        *(uint32_t*)(vb + byte) = pk;
      }
    }
  };

  f32x16 Yacc[2] = {};  // Y^T[d][q=q5], d = (r&3)+8*(r>>2)+4h+32*dh
  float m_run = -__builtin_inff(), l_run = 0.f;

  // prologue: stage tile 0
  stageK(0, 0);
  loadV(0);
  writeV(0);
  __syncthreads();

  for (int t = 0; t < NT; ++t) {
    const int cur = t & 1;
    const char* Kb = smem + cur * 16384;
    const char* Vb = smem + 32768 + cur * 16384;
    // prefetch next tile: K direct-to-LDS (other buffer), V to regs
    if (t + 1 < NT) {
      stageK((t + 1) * 128, cur ^ 1);
      loadV((t + 1) * 128);
    }

    // ---- S^T = mfma(A=K, B=Q): lane owns q=q5; 64 scores (keys j*32 + kr(r,h))
    float p_[64];
#pragma unroll
    for (int j = 0; j < 4; ++j) {
      f32x16 S = {};
#pragma unroll
      for (int tt = 0; tt < 4; ++tt) {
        int row = j * 32 + q5;
        int chunk = (2 * tt + h) ^ (q5 & 7);
        bf16x8 kf = *(const bf16x8*)(Kb + row * 128 + 16 * chunk);
        S = __builtin_amdgcn_mfma_f32_32x32x16_bf16(kf, aq[tt], S, 0, 0, 0);
      }
#pragma unroll
      for (int r = 0; r < 16; ++r) p_[j * 16 + r] = S[r];
    }

    // ---- online softmax (scale 1/8); 4-chain trees, defer-max rescale
    float m0 = p_[0], m1 = p_[1], m2 = p_[2], m3 = p_[3];
#pragma unroll
    for (int i = 4; i < 64; i += 4) {
      m0 = fmaxf(m0, p_[i]);     m1 = fmaxf(m1, p_[i + 1]);
      m2 = fmaxf(m2, p_[i + 2]); m3 = fmaxf(m3, p_[i + 3]);
    }
    float mx = fmaxf(fmaxf(m0, m1), fmaxf(m2, m3));
    mx = fmaxf(mx, __shfl_xor(mx, 32));
    mx *= 0.125f;
    if (!__all(mx <= m_run + 5.545f)) {  // defer rescale while P <= e^5.545 ~ 256
      float mnew = fmaxf(m_run, mx);
      float corr = __expf(m_run - mnew);
      l_run *= corr;
#pragma unroll
      for (int dh = 0; dh < 2; ++dh)
#pragma unroll
        for (int r = 0; r < 16; ++r) Yacc[dh][r] *= corr;
      m_run = mnew;
    }
    float rs0 = 0.f, rs1 = 0.f, rs2 = 0.f, rs3 = 0.f;
#pragma unroll
    for (int i = 0; i < 64; i += 4) {
      float e0 = __expf(fmaf(p_[i], 0.125f, -m_run));
      float e1 = __expf(fmaf(p_[i + 1], 0.125f, -m_run));
      float e2 = __expf(fmaf(p_[i + 2], 0.125f, -m_run));
      float e3 = __expf(fmaf(p_[i + 3], 0.125f, -m_run));
      p_[i] = e0; p_[i + 1] = e1; p_[i + 2] = e2; p_[i + 3] = e3;
      rs0 += e0; rs1 += e1; rs2 += e2; rs3 += e3;
    }
    float rs = (rs0 + rs1) + (rs2 + rs3);
    rs += __shfl_xor(rs, 32);
    l_run += rs;

    // ---- Y^T += mfma(A=V^T, B=P^T) per 16-key sub-tile
#pragma unroll
    for (int j = 0; j < 4; ++j) {
#pragma unroll
      for (int s = 0; s < 2; ++s) {
        const float* ps = p_ + j * 16 + s * 8;
        uint32_t pk01 = pack2(ps[0], ps[1]);
        uint32_t pk23 = pack2(ps[2], ps[3]);
        uint32_t pk45 = pack2(ps[4], ps[5]);
        uint32_t pk67 = pack2(ps[6], ps[7]);
        uint32_t fa = (uint32_t)__shfl_xor((int)(h ? pk01 : pk45), 32);
        uint32_t fb = (uint32_t)__shfl_xor((int)(h ? pk23 : pk67), 32);
        u32x4 pw;
        pw[0] = h ? fa : pk01;
        pw[1] = h ? fb : pk23;
        pw[2] = h ? pk45 : fa;
        pw[3] = h ? pk67 : fb;
        bf16x8 pfrag = __builtin_bit_cast(bf16x8, pw);
        int keyb = j * 64 + s * 32 + 16 * h;  // (32j+16s+8h) keys * 2B
#pragma unroll
        for (int dh = 0; dh < 2; ++dh) {
          int d = dh * 32 + q5;
          int byte = (d * 256 + keyb) ^ vswz(d);
          bf16x8 vf = *(const bf16x8*)(Vb + byte);
          Yacc[dh] = __builtin_amdgcn_mfma_f32_32x32x16_bf16(vf, pfrag, Yacc[dh], 0, 0, 0);
        }
      }
    }
    // commit next tile's V (regs -> LDS, other buffer); waits its global loads
    if (t + 1 < NT) writeV(cur ^ 1);
    __syncthreads();
  }

  // ---- epilogue: scale by 1/l, transpose via LDS (reuse smem), coalesced stores
  float rl = __builtin_amdgcn_rcpf(l_run);
  char* yb = smem + w * (32 * 144);  // per-wave [32 q][72 bf16] region (144B rows)
#pragma unroll
  for (int dh = 0; dh < 2; ++dh)
#pragma unroll
    for (int a = 0; a < 4; ++a) {
      bf16x4 pkv;
#pragma unroll
      for (int i = 0; i < 4; ++i) pkv[i] = (__bf16)(Yacc[dh][a * 4 + i] * rl);
      int d0 = a * 8 + 4 * h + 32 * dh;
      *(bf16x4*)(yb + q5 * 144 + d0 * 2) = pkv;
    }
  __bf16* Yrow = Yb + (size_t)(b * TT + qb * 128 + w * 32) * 768 + hd * 64;
#pragma unroll
  for (int k = 0; k < 4; ++k) {
    int chunk = k * 64 + lane;
    int qr = chunk >> 3, sr = chunk & 7;
    bf16x8 vv = *(const bf16x8*)(yb + qr * 144 + sr * 16);
    *(bf16x8*)(Yrow + (size_t)qr * 768 + sr * 8) = vv;
  }
}

extern "C" void kernel_launch(void* const* d_in, const int* in_sizes, int n_in,
                              void* d_out, int out_size, void* d_ws, size_t ws_size,
                              hipStream_t stream) {
  const float* x = (const float*)d_in[0];
  const float* cosT = (const float*)d_in[1];
  const float* sinT = (const float*)d_in[2];
  const float* wq = (const float*)d_in[3];
  const float* wk = (const float*)d_in[4];
  const float* wv = (const float*)d_in[5];
  const float* wp = (const float*)d_in[6];

  char* ws = (char*)d_ws;
  __bf16* xb   = (__bf16*)(ws);                 //  6,291,456 B  (4096x768 bf16)
  __bf16* WT   = (__bf16*)(ws + 6291456);       //  4,718,592 B  (3072x768 bf16)
  __bf16* QKVb = (__bf16*)(ws + 11010048);      // 18,874,368 B  (4096x2304 bf16)
  __bf16* Yb   = (__bf16*)(ws + 29884416);      //  6,291,456 B  (4096x768 bf16)

  cvt_x_k<<<2048, 256, 0, stream>>>(x, xb, (4096 * 768) / 4);
  wtrans_k<<<dim3(24, 24, 4), dim3(32, 8), 0, stream>>>(wq, wk, wv, wp, WT);
  // fused QKV gemm: M=4096, N=2304, K=768
  gemm_k<1, 128><<<dim3(18, 32), 256, 0, stream>>>(xb, WT, (void*)QKVb, cosT, sinT,
                                                   768, 768, 768, 2304);
  attn_k<<<dim3(16, 24), 256, 0, stream>>>(QKVb, Yb);
  // proj gemm: M=4096, N=768, K=768, 128x64 tiles -> 384 blocks
  gemm_k<0, 64><<<dim3(12, 32), 256, 0, stream>>>(Yb, WT + (size_t)2304 * 768, d_out,
                                                  nullptr, nullptr, 768, 768, 768, 768);
}